// Round 6
// baseline (298.187 us; speedup 1.0000x reference)
//
#include <hip/hip_runtime.h>

typedef unsigned char u8;
typedef float f32x4 __attribute__((ext_vector_type(4)));

#define P_OUT 29791      // 31^3
#define NCH   512

// ---- pack 4 fp32 -> 4 fp8 e4m3 (RNE, OCP) ----
__device__ __forceinline__ unsigned pk4_fp8(float a, float b, float c, float d) {
  int v = __builtin_amdgcn_cvt_pk_fp8_f32(a, b, 0, false);   // low word
  v = __builtin_amdgcn_cvt_pk_fp8_f32(c, d, v, true);        // high word
  return (unsigned)v;
}

// ---- w-prep: 512 rows, 16 rows/block, 32 blocks ----
__global__ void wprep_kernel(const float* __restrict__ w,
                             u8* __restrict__ wb, float* __restrict__ wsq) {
  const int tid = threadIdx.x;
  const int g = blockIdx.x * 16 + (tid >> 4);  // 0..511
  const int c = tid & 15;
  const float4* wr = (const float4*)(w + g * 128 + c * 8);
  float4 f0 = wr[0], f1 = wr[1];
  float s = f0.x*f0.x + f0.y*f0.y + f0.z*f0.z + f0.w*f0.w
          + f1.x*f1.x + f1.y*f1.y + f1.z*f1.z + f1.w*f1.w;
#pragma unroll
  for (int m = 1; m < 16; m <<= 1) s += __shfl_xor(s, m, 64);
  uint2 pk;
  pk.x = pk4_fp8(f0.x, f0.y, f0.z, f0.w);
  pk.y = pk4_fp8(f1.x, f1.y, f1.z, f1.w);
  *(uint2*)(wb + g * 128 + c * 8) = pk;
  if (c == 0) wsq[g] = s;
}

// async global->LDS, 16 B per lane, lands at ldsbase + lane*16
#define GLDS(g, l) __builtin_amdgcn_global_load_lds(                         \
    (const __attribute__((address_space(1))) unsigned int*)(g),              \
    (__attribute__((address_space(3))) unsigned int*)(l), 16, 0, 0)

// ---- Fused unfold + pack-to-LDS + GEMM + epilogue ----
// Tile = (nb, ct, d, hb): 128 ch x 124 p (4 h-rows x 31 w; hb=7 -> 93).
// Phase 1: GLDS-stage Ws (fp8 w tile) + Xs (x slab [16c][2kd][5hq][32w]).
// Phase 2: cooperative pack Xs -> Ys fp8 [row][swizzled 16B chunks]:
//   thread owns row=tid&127, parity pb=tid>>7; 8 its over c=2*it+pb.
//   Reads conflict-free (consecutive rows across lanes); 8B writes at
//   swizzle pos (it ^ (row&7)) -> 2-way max. ysq partials -> Yq[2][128].
// Phase 3: MFMA, A(Ws) + B(Ys) both via the r4-verified b64 swizzled reads.
// Phase 4: epilogue out = exp(2*cross - ysq - wsq), fire-and-forget stores.
// XCD-chunked bijective decode: 3968 = 8*496.
__global__ __launch_bounds__(256, 3)
void gauss_fused_kernel(const float* __restrict__ x,
                        const u8* __restrict__ wb,
                        const float* __restrict__ wsq,
                        float* __restrict__ out) {
  __shared__ __align__(16) u8 Ws[128 * 128];     // w tile [ch][k], 16 KB
  __shared__ __align__(16) float Xs[5120];       // x slab, 20 KB
  __shared__ __align__(16) u8 Ys[128 * 128];     // packed y tile, 16 KB
  __shared__ float Yq[2][128];                   // ysq partials, 1 KB

  const int bid = blockIdx.x;
  const int tile = (bid & 7) * 496 + (bid >> 3);   // bijective XCD chunking
  const unsigned nb = (unsigned)tile / 992u;       // 4 batches
  const unsigned rem = (unsigned)tile - nb * 992u;
  const unsigned ct = rem / 248u;                  // 4 ch tiles
  const unsigned r2 = rem - ct * 248u;
  const unsigned d  = r2 >> 3;                     // 31 d values
  const unsigned hb = r2 & 7;                      // 8 h-blocks, fastest
  const int h0 = hb * 4;
  const int nh = (h0 + 4 <= 31) ? 4 : (31 - h0);   // 4 (hb<7) or 3 (hb=7)
  const int nrows = nh * 31;                       // 124 or 93
  const int c0 = ct * 128;
  const int tp0 = d * 961 + h0 * 31;               // tile's base p

  const int tid = threadIdx.x;
  const int wid = tid >> 6;
  const int lane = tid & 63;
  const int quad = lane >> 4;
  const int col = lane & 15;
  const int wch = wid & 1;   // wave ch-half
  const int wp = wid >> 1;   // wave p-half

  // ---- stage W tile: 1024 chunks, swizzled (r4 verbatim) ----
#pragma unroll
  for (int t = 0; t < 4; ++t) {
    const int Lb = (wid * 4 + t) * 64;
    const int L = Lb + lane;
    const int row = L >> 3;
    const int jc = (L & 7) ^ (row & 7);
    GLDS(wb + (size_t)(c0 + row) * 128 + jc * 16, &Ws[Lb * 16]);
  }

  // ---- stage x slab: 160 rows of 128 B = 1280 chunks, 5 rounds ----
#pragma unroll
  for (int t = 0; t < 5; ++t) {
    const int Lb = t * 256 + wid * 64;
    const int L = Lb + lane;
    const int row = L >> 3;                // 0..159
    const int jc = L & 7;
    const unsigned c = (unsigned)row / 10u;
    const unsigned rr = (unsigned)row - c * 10u;
    const unsigned kd = rr / 5u;
    const unsigned hq = rr - kd * 5u;
    const int hg = h0 + (int)hq;
    const int hcl = (hg < 31) ? hg : 31;
    GLDS(x + (((size_t)(nb * 16 + c)) << 15) + (d + kd) * 1024 + hcl * 32 + jc * 4,
         &Xs[Lb * 4]);
  }

  // ---- pack-index precompute (hides under GLDS flight) ----
  const int prow = tid & 127;            // this thread's y-row
  const int pbh = tid >> 7;              // channel parity (0/1)
  const unsigned hh2 = (unsigned)prow / 31u;
  const unsigned wv2 = (unsigned)prow - hh2 * 31u;
  const int xo = (int)(hh2 * 32 + wv2);  // clamped below by prow<nrows guard

  f32x4 acc[4][4];
#pragma unroll
  for (int i = 0; i < 4; ++i)
#pragma unroll
    for (int j = 0; j < 4; ++j) acc[i][j] = (f32x4){0.f, 0.f, 0.f, 0.f};

  __syncthreads();   // drains all GLDS

  // ---- phase 2: cooperative pack Xs -> Ys (+ ysq partials) ----
  if (prow < nrows) {
    float sqp = 0.f;
    const int wbase = prow * 128 + pbh * 8;
    const int rsw = prow & 7;
#pragma unroll
    for (int it = 0; it < 8; ++it) {
      const int c = it * 2 + pbh;
      const float* pB = &Xs[c * 320 + xo];
      // k-elem order = (kd,kh,kw): strides kd=160, kh=32, kw=1 floats
      const float v0 = pB[0],   v1 = pB[1],   v2 = pB[32],  v3 = pB[33];
      const float v4 = pB[160], v5 = pB[161], v6 = pB[192], v7 = pB[193];
      sqp += v0*v0 + v1*v1 + v2*v2 + v3*v3 + v4*v4 + v5*v5 + v6*v6 + v7*v7;
      uint2 pk;
      pk.x = pk4_fp8(v0, v1, v2, v3);
      pk.y = pk4_fp8(v4, v5, v6, v7);
      *(uint2*)&Ys[wbase + ((it ^ rsw) << 4)] = pk;
    }
    Yq[pbh][prow] = sqp;
  }

  __syncthreads();   // Ys + Yq visible to all

  // ---- phase 3: MFMA (A & B via r4-verified swizzled b64 reads) ----
  const int c16b = quad >> 1;
  const int hoff = (quad & 1) * 8;
#pragma unroll
  for (int ks = 0; ks < 4; ++ks) {
    long long a[4], b[4];
#pragma unroll
    for (int i = 0; i < 4; ++i) {
      const int rowA = wch * 64 + i * 16 + col;
      const int pa = (ks * 2 + c16b) ^ (rowA & 7);
      a[i] = *(const long long*)&Ws[rowA * 128 + pa * 16 + hoff];
      const int rowB = wp * 64 + i * 16 + col;
      const int pb = (ks * 2 + c16b) ^ (rowB & 7);
      b[i] = *(const long long*)&Ys[rowB * 128 + pb * 16 + hoff];
    }
#pragma unroll
    for (int i = 0; i < 4; ++i)
#pragma unroll
      for (int j = 0; j < 4; ++j)
        acc[i][j] = __builtin_amdgcn_mfma_f32_16x16x32_fp8_fp8(a[i], b[j],
                                                               acc[i][j], 0, 0, 0);
  }

  // ---- phase 4: epilogue, fire-and-forget stores ----
  int rb[4];
  float ysv[4];
#pragma unroll
  for (int j = 0; j < 4; ++j) {
    rb[j] = wp * 64 + j * 16 + col;
    const int rc = (rb[j] < 124) ? rb[j] : 123;   // stay in Yq bounds
    ysv[j] = Yq[0][rc] + Yq[1][rc];
  }
#pragma unroll
  for (int i = 0; i < 4; ++i) {
#pragma unroll
    for (int r = 0; r < 4; ++r) {
      const int ch = c0 + wch * 64 + i * 16 + quad * 4 + r;
      const float wsv = wsq[ch];
      float* ob = out + ((size_t)(nb * NCH + ch)) * P_OUT;
#pragma unroll
      for (int j = 0; j < 4; ++j)
        if (rb[j] < nrows)
          ob[tp0 + rb[j]] = __expf(2.f * acc[i][j][r] - ysv[j] - wsv);
    }
  }
}

extern "C" void kernel_launch(void* const* d_in, const int* in_sizes, int n_in,
                              void* d_out, int out_size, void* d_ws, size_t ws_size,
                              hipStream_t stream) {
  const float* x = (const float*)d_in[0];
  const float* w = (const float*)d_in[1];
  float* out = (float*)d_out;
  char* ws = (char*)d_ws;
  // workspace: wb 512*128 fp8 = 65,536 B ; wsq 512*4 = 2,048 B
  u8* wb     = (u8*)ws;
  float* wsq = (float*)(ws + 65536);

  wprep_kernel<<<32, 256, 0, stream>>>(w, wb, wsq);
  gauss_fused_kernel<<<3968, 256, 0, stream>>>(x, wb, wsq, out);
}

// Round 7
// 278.892 us; speedup vs baseline: 1.0692x; 1.0692x over previous
//
#include <hip/hip_runtime.h>

typedef unsigned char u8;
typedef float f32x4 __attribute__((ext_vector_type(4)));

#define P_OUT 29791      // 31^3
#define NCH   512

// ---- pack 4 fp32 -> 4 fp8 e4m3 (RNE, OCP) ----
__device__ __forceinline__ unsigned pk4_fp8(float a, float b, float c, float d) {
  int v = __builtin_amdgcn_cvt_pk_fp8_f32(a, b, 0, false);   // low word
  v = __builtin_amdgcn_cvt_pk_fp8_f32(c, d, v, true);        // high word
  return (unsigned)v;
}

// ---- w-prep: 512 rows, 16 rows/block, 32 blocks ----
__global__ void wprep_kernel(const float* __restrict__ w,
                             u8* __restrict__ wb, float* __restrict__ wsq) {
  const int tid = threadIdx.x;
  const int g = blockIdx.x * 16 + (tid >> 4);  // 0..511
  const int c = tid & 15;
  const float4* wr = (const float4*)(w + g * 128 + c * 8);
  float4 f0 = wr[0], f1 = wr[1];
  float s = f0.x*f0.x + f0.y*f0.y + f0.z*f0.z + f0.w*f0.w
          + f1.x*f1.x + f1.y*f1.y + f1.z*f1.z + f1.w*f1.w;
#pragma unroll
  for (int m = 1; m < 16; m <<= 1) s += __shfl_xor(s, m, 64);
  uint2 pk;
  pk.x = pk4_fp8(f0.x, f0.y, f0.z, f0.w);
  pk.y = pk4_fp8(f1.x, f1.y, f1.z, f1.w);
  *(uint2*)(wb + g * 128 + c * 8) = pk;
  if (c == 0) wsq[g] = s;
}

// async global->LDS, 16 B per lane, lands at ldsbase + lane*16
#define GLDS(g, l) __builtin_amdgcn_global_load_lds(                         \
    (const __attribute__((address_space(1))) unsigned int*)(g),              \
    (__attribute__((address_space(3))) unsigned int*)(l), 16, 0, 0)

// ---- Fused unfold + GEMM + epilogue, ct-loop version ----
// One block per (nb, d, hb) slab: 124 p-rows x ALL 512 channels.
// Xs slab staged ONCE; B-fragments packed ONCE into 32 VGPRs (r5-verbatim
// pack: k = ks*32+quad*8+j, j=(kd,kh,kw), c = ks*4+quad); then ct = 0..3
// with double-buffered Ws (GLDS prefetch issued right after each barrier,
// drained by the next one). acc scoped per-ct. Epilogue/MFMA r5-verbatim.
// XCD-chunked bijective decode: 992 = 8*124, hb fastest -> consecutive
// same-XCD blocks write adjacent output p-ranges (L2 write locality).
__global__ __launch_bounds__(256, 2)
void gauss_fused_kernel(const float* __restrict__ x,
                        const u8* __restrict__ wb,
                        const float* __restrict__ wsq,
                        float* __restrict__ out) {
  __shared__ __align__(16) u8 Ws[2][128 * 128];   // w tiles, 2 x 16 KB
  __shared__ __align__(16) float Xs[5120];        // x slab, 20 KB

  const int bid = blockIdx.x;
  const int tile = (bid & 7) * 124 + (bid >> 3);   // bijective XCD chunking
  const unsigned nb = (unsigned)tile / 248u;       // 4 batches
  const unsigned r2 = (unsigned)tile - nb * 248u;
  const unsigned d  = r2 >> 3;                     // 31 d values
  const unsigned hb = r2 & 7;                      // 8 h-blocks, fastest
  const int h0 = hb * 4;
  const int nh = (h0 + 4 <= 31) ? 4 : (31 - h0);   // 4 (hb<7) or 3 (hb=7)
  const int nrows = nh * 31;                       // 124 or 93
  const int tp0 = d * 961 + h0 * 31;               // tile's base p

  const int tid = threadIdx.x;
  const int wid = tid >> 6;
  const int lane = tid & 63;
  const int quad = lane >> 4;
  const int col = lane & 15;
  const int wch = wid & 1;   // wave ch-half
  const int wp = wid >> 1;   // wave p-half

  // ---- stage Ws[0] (ct=0): 1024 swizzled chunks (r4/r5 verbatim) ----
#pragma unroll
  for (int t = 0; t < 4; ++t) {
    const int Lb = (wid * 4 + t) * 64;
    const int L = Lb + lane;
    const int row = L >> 3;
    const int jc = (L & 7) ^ (row & 7);
    GLDS(wb + (size_t)row * 128 + jc * 16, &Ws[0][Lb * 16]);
  }

  // ---- stage x slab [16c][2kd][5hq][32w]: 1280 chunks, 5 rounds ----
#pragma unroll
  for (int t = 0; t < 5; ++t) {
    const int Lb = t * 256 + wid * 64;
    const int L = Lb + lane;
    const int row = L >> 3;                // 0..159
    const int jc = L & 7;
    const unsigned c = (unsigned)row / 10u;
    const unsigned rr = (unsigned)row - c * 10u;
    const unsigned kd = rr / 5u;
    const unsigned hq = rr - kd * 5u;
    const int hg = h0 + (int)hq;
    const int hcl = (hg < 31) ? hg : 31;   // hb=7 tail slot, unused
    GLDS(x + (((size_t)(nb * 16 + c)) << 15) + (d + kd) * 1024 + hcl * 32 + jc * 4,
         &Xs[Lb * 4]);
  }

  // ---- per-lane p-row decode (hides under GLDS flight) ----
  int rb[4];
  int xoff[4];
#pragma unroll
  for (int j = 0; j < 4; ++j) {
    rb[j] = wp * 64 + j * 16 + col;
    const unsigned rc = (unsigned)((rb[j] < nrows) ? rb[j] : (nrows - 1));
    const unsigned hh = rc / 31u;
    const unsigned wv = rc - hh * 31u;
    xoff[j] = (int)(hh * 32 + wv);
  }

  __syncthreads();   // drains Ws[0] + Xs

  // ---- prefetch Ws[1] (ct=1); flies under the B-pack below ----
#pragma unroll
  for (int t = 0; t < 4; ++t) {
    const int Lb = (wid * 4 + t) * 64;
    const int L = Lb + lane;
    const int row = L >> 3;
    const int jc = (L & 7) ^ (row & 7);
    GLDS(wb + (size_t)(128 + row) * 128 + jc * 16, &Ws[1][Lb * 16]);
  }

  // ---- build B fragments ONCE into registers (r5-verbatim pack) ----
  long long B[4][4];
  float sq[4] = {0.f, 0.f, 0.f, 0.f};
#pragma unroll
  for (int ks = 0; ks < 4; ++ks) {
    const int cc = ks * 4 + quad;          // channel for this lane's k-chunk
    const float* xb = &Xs[cc * 320];       // [kd][hq][32] view
#pragma unroll
    for (int j = 0; j < 4; ++j) {
      const float* pB = xb + xoff[j];
      // k-elem order = (kd,kh,kw): strides kd=160, kh=32, kw=1 floats
      const float v0 = pB[0],   v1 = pB[1],   v2 = pB[32],  v3 = pB[33];
      const float v4 = pB[160], v5 = pB[161], v6 = pB[192], v7 = pB[193];
      sq[j] += v0*v0 + v1*v1 + v2*v2 + v3*v3 + v4*v4 + v5*v5 + v6*v6 + v7*v7;
      const unsigned lo = pk4_fp8(v0, v1, v2, v3);
      const unsigned hi = pk4_fp8(v4, v5, v6, v7);
      B[ks][j] = (long long)(((unsigned long long)hi << 32) | lo);
    }
  }
  // full ysq per row: reduce partials across the 4 quads
#pragma unroll
  for (int j = 0; j < 4; ++j) {
    sq[j] += __shfl_xor(sq[j], 16, 64);
    sq[j] += __shfl_xor(sq[j], 32, 64);
  }

  const int c16b = quad >> 1;
  const int hoff = (quad & 1) * 8;

  // ---- ct loop: MFMA + epilogue per 128-ch tile, Ws double-buffered ----
#pragma unroll
  for (int ctit = 0; ctit < 4; ++ctit) {
    const u8* Wcur = Ws[ctit & 1];

    f32x4 acc[4][4];
#pragma unroll
    for (int i = 0; i < 4; ++i)
#pragma unroll
      for (int j = 0; j < 4; ++j) acc[i][j] = (f32x4){0.f, 0.f, 0.f, 0.f};

#pragma unroll
    for (int ks = 0; ks < 4; ++ks) {
      long long a[4];
#pragma unroll
      for (int i = 0; i < 4; ++i) {
        const int rowA = wch * 64 + i * 16 + col;
        const int pa = (ks * 2 + c16b) ^ (rowA & 7);
        a[i] = *(const long long*)&Wcur[rowA * 128 + pa * 16 + hoff];
      }
#pragma unroll
      for (int i = 0; i < 4; ++i)
#pragma unroll
        for (int j = 0; j < 4; ++j)
          acc[i][j] = __builtin_amdgcn_mfma_f32_16x16x32_fp8_fp8(a[i], B[ks][j],
                                                                 acc[i][j], 0, 0, 0);
    }

    // epilogue for ct=ctit: out = exp(2*cross - ysq - wsq), fire-and-forget
    const int c0 = ctit * 128;
#pragma unroll
    for (int i = 0; i < 4; ++i) {
#pragma unroll
      for (int r = 0; r < 4; ++r) {
        const int ch = c0 + wch * 64 + i * 16 + quad * 4 + r;
        const float wsv = wsq[ch];
        float* ob = out + ((size_t)(nb * NCH + ch)) * P_OUT;
#pragma unroll
        for (int j = 0; j < 4; ++j)
          if (rb[j] < nrows)
            ob[tp0 + rb[j]] = __expf(2.f * acc[i][j][r] - sq[j] - wsv);
      }
    }

    // rotate buffers: barrier frees Wcur + drains the in-flight prefetch;
    // then refill Wcur with ct+2.
    if (ctit < 3) {
      __syncthreads();
      if (ctit < 2) {
        u8* Wnext = Ws[ctit & 1];          // the buffer just consumed
        const int ctn = ctit + 2;
#pragma unroll
        for (int t = 0; t < 4; ++t) {
          const int Lb = (wid * 4 + t) * 64;
          const int L = Lb + lane;
          const int row = L >> 3;
          const int jc = (L & 7) ^ (row & 7);
          GLDS(wb + (size_t)(ctn * 128 + row) * 128 + jc * 16, &Wnext[Lb * 16]);
        }
      }
    }
  }
}

extern "C" void kernel_launch(void* const* d_in, const int* in_sizes, int n_in,
                              void* d_out, int out_size, void* d_ws, size_t ws_size,
                              hipStream_t stream) {
  const float* x = (const float*)d_in[0];
  const float* w = (const float*)d_in[1];
  float* out = (float*)d_out;
  char* ws = (char*)d_ws;
  // workspace: wb 512*128 fp8 = 65,536 B ; wsq 512*4 = 2,048 B
  u8* wb     = (u8*)ws;
  float* wsq = (float*)(ws + 65536);

  wprep_kernel<<<32, 256, 0, stream>>>(w, wb, wsq);
  gauss_fused_kernel<<<992, 256, 0, stream>>>(x, wb, wsq, out);
}